// Round 5
// baseline (14079.196 us; speedup 1.0000x reference)
//
#include <hip/hip_runtime.h>

typedef __attribute__((ext_vector_type(8))) short bf16x8;
typedef __attribute__((ext_vector_type(4))) float f32x4;

#define L2E 1.4426950408889634f

__device__ __forceinline__ short f2bf(float x){
  unsigned u = __builtin_bit_cast(unsigned, x);
  u += 0x7fffu + ((u >> 16) & 1u);
  return (short)(u >> 16);
}
__device__ __forceinline__ float sigm(float x){
  float e = __builtin_amdgcn_exp2f(-x * L2E);
  return __builtin_amdgcn_rcpf(1.0f + e);
}
__device__ __forceinline__ float tanh_(float x){
  float e = __builtin_amdgcn_exp2f(x * (2.0f * L2E));
  return 1.0f - 2.0f * __builtin_amdgcn_rcpf(1.0f + e);
}

// LDS-only barrier: drain DS ops, raw s_barrier, no vmcnt(0) drain.
__device__ __forceinline__ void wg_barrier(){
  asm volatile("s_waitcnt lgkmcnt(0)" ::: "memory");
  __builtin_amdgcn_s_barrier();
  asm volatile("" ::: "memory");
}

// Cell-split pipelined recurrence, 512 threads / 8 waves:
//   waves 0-3 (grp0): cell1(s)   -- each wave owns units [32wv,32wv+32) of Whh1
//   waves 4-7 (grp1): cell0(s-1) -- each wave owns units [32wv,32wv+32) of Whh0
// REGISTER BUDGET (the r4 lesson): a 16-wave WG caps at 128 regs/thread ->
// forced spill/remat (24.7 GB HBM refetch). 8-wave WG at <=256 regs/thread:
// 128 weight regs + 32 acc + ~60 working set fits with headroom -> no spill.
// Both groups read the SAME A-operand hb[p] = h1n(s-1) (cell1's h-input IS
// h1n(s-1); cell0's state inputs are h1n(s-1), c1n(s-1) -- not its own h0),
// so ONE lgkm-only barrier per step. cell1 hands c1n to cell0 via the cst
// ping-pong; cell0's only cross-step product is the scalar x_h partial.
// No global ops on the step path: x_c + loss recomputed per 16-step chunk
// from sA + xh_hist, flushed by wave 7 (non-loader wave).
__global__ __launch_bounds__(512, 2)
void rios_main(const float* __restrict__ values, const float* __restrict__ masks,
               const float* __restrict__ deltas,
               const float* __restrict__ Wih0, const float* __restrict__ Whh0,
               const float* __restrict__ bih0, const float* __restrict__ bhh0,
               const float* __restrict__ Wih1, const float* __restrict__ Whh1,
               const float* __restrict__ bih1, const float* __restrict__ bhh1,
               const float* __restrict__ td_W, const float* __restrict__ td_b,
               const float* __restrict__ hr_W, const float* __restrict__ hr_b,
               float* __restrict__ out, float* __restrict__ lossws)
{
  __shared__ short hb[2][16][136];    // h1n ping-pong by parity: [buf][batch m][unit k]
  __shared__ float cst[2][16][132];   // c1n ping-pong: [buf][batch m][unit]
  __shared__ float xh_part[2][4][16]; // per-grp1-wave partial of h0 . hr_W
  __shared__ float sA[2][5][16][16];  // scalar chunks: [buf][v0,v1,v2,mask,delta2][tt][m]
  __shared__ float xh_hist[16][16];   // per-step x_h (w4 c==0), consumed by flush

  const int tid = threadIdx.x;
  const int w   = tid >> 6;     // 0..7
  const int grp = w >> 2;       // 0 = cell1(s), 1 = cell0(s-1)
  const int wv  = w & 3;        // wave within group; owns units [32wv, 32wv+32)
  const int l   = tid & 63;
  const int q   = l >> 4;
  const int c   = l & 15;
  const int q4  = q << 2;
  const int u0  = (wv << 5) + c;      // unit for ct=0; ct=1 adds 16
  const long long bb = (long long)blockIdx.x * 16;

  // ---- per-group persistent weight fragments (B-operand: col=lane&15, k=(lane>>4)*8+j)
  const float* Whh = grp == 0 ? Whh1 : Whh0;
  const float* Wih = grp == 0 ? Wih1 : Wih0;
  const float* bih = grp == 0 ? bih1 : bih0;
  const float* bhh = grp == 0 ? bhh1 : bhh0;

  bf16x8 wf[4][2][4];   // [gate][ct][ktile] -- 128 regs
  #pragma unroll
  for (int gi = 0; gi < 4; ++gi)
    #pragma unroll
    for (int ct = 0; ct < 2; ++ct)
      #pragma unroll
      for (int kt = 0; kt < 4; ++kt){
        const float* rp = Whh + (((gi << 7) + u0 + (ct << 4)) << 7) + (kt << 5) + (q << 3);
        bf16x8 f;
        #pragma unroll
        for (int j = 0; j < 8; ++j) f[j] = f2bf(rp[j]);
        wf[gi][ct][kt] = f;
      }
  float wi[4][2][2], bs[4][2];
  #pragma unroll
  for (int gi = 0; gi < 4; ++gi)
    #pragma unroll
    for (int ct = 0; ct < 2; ++ct){
      int rg = (gi << 7) + u0 + (ct << 4);
      wi[gi][ct][0] = Wih[rg * 2];
      wi[gi][ct][1] = Wih[rg * 2 + 1];
      bs[gi][ct]    = bih[rg] + bhh[rg];
    }
  float tdw[2] = {0.f, 0.f}, tdbv[2] = {0.f, 0.f}, hrw[2] = {0.f, 0.f};
  #pragma unroll
  for (int ct = 0; ct < 2; ++ct){
    int uc = u0 + (ct << 4);
    if (grp == 0){ tdw[ct] = td_W[uc]; tdbv[ct] = td_b[uc]; }
    else         { hrw[ct] = hr_W[uc]; }
  }
  const float hrb = hr_b[0];

  // ---- zero initial state (h1(-1)=0, c1(-1)=0; xh_part both parities 0)
  {
    short* hz = &hb[0][0][0];
    for (int i = tid; i < 2 * 16 * 136; i += 512) hz[i] = 0;
    float* cz = &cst[0][0][0];
    for (int i = tid; i < 2 * 16 * 132; i += 512) cz[i] = 0.f;
    if (tid < 128) ((float*)xh_part)[tid] = 0.f;
  }

  // ---- chunk loader thread roles (waves 0-6; wave 7 is the flush wave)
  const int isV = (tid < 192);
  const int isD = (tid >= 192 && tid < 384);
  const int isM = (tid >= 384 && tid < 448);
  int lb = 0, lp = 0;
  if (isV){ lb = tid / 12;        lp = tid % 12; }
  else if (isD){ lb = (tid-192)/12; lp = (tid-192)%12; }
  else if (isM){ lb = (tid-384)/4;  lp = (tid-384)%4; }
  const float* ldbase = nullptr;
  if (isV)      ldbase = values + ((bb + lb) * 2048LL) * 3 + lp * 4;
  else if (isD) ldbase = deltas + ((bb + lb) * 2048LL) * 3 + lp * 4;
  else if (isM) ldbase = masks  +  (bb + lb) * 2048LL      + lp * 4;

  auto write_stage = [&](int buf, f32x4 r){
    if (isV){
      #pragma unroll
      for (int j = 0; j < 4; ++j){ int idx = lp * 4 + j; sA[buf][idx % 3][idx / 3][lb] = r[j]; }
    } else if (isD){
      #pragma unroll
      for (int j = 0; j < 4; ++j){ int idx = lp * 4 + j; if (idx % 3 == 2) sA[buf][4][idx / 3][lb] = r[j]; }
    } else if (isM){
      #pragma unroll
      for (int j = 0; j < 4; ++j){ sA[buf][3][lp * 4 + j][lb] = r[j]; }
    }
  };

  // prologue: chunk 0
  if (tid < 448){
    f32x4 st = *(const f32x4*)(ldbase);
    write_stage(0, st);
  }
  __syncthreads();

  f32x4 c1[2] = {{0.f,0.f,0.f,0.f},{0.f,0.f,0.f,0.f}};   // live only in grp0

  for (int cc = 0; cc < 128; ++cc){
    const int cb = cc & 1;
    f32x4 nst;
    #pragma unroll 1
    for (int tt = 0; tt < 16; ++tt){
      const int s = (cc << 4) + tt;
      const int p = tt & 1;                         // == s & 1
      const int ob  = (tt == 0) ? (cb ^ 1) : cb;    // buffer holding step s-1 scalars
      const int ott = (tt == 0) ? 15 : (tt - 1);

      if (grp == 0){
        // ================= cell1(s) : A-operand hb[p] = h1n(s-1) ================
        f32x4 v0v = *(const f32x4*)&sA[cb][0][tt][q4];
        f32x4 v1v = *(const f32x4*)&sA[cb][1][tt][q4];
        f32x4 dv  = *(const f32x4*)&sA[cb][4][tt][q4];
        f32x4 acc[4][2];
        #pragma unroll
        for (int gi = 0; gi < 4; ++gi)
          #pragma unroll
          for (int ct = 0; ct < 2; ++ct)
            #pragma unroll
            for (int r = 0; r < 4; ++r)
              acc[gi][ct][r] = fmaf(v0v[r], wi[gi][ct][0], fmaf(v1v[r], wi[gi][ct][1], bs[gi][ct]));
        #pragma unroll
        for (int kt = 0; kt < 4; ++kt){
          bf16x8 af = *(const bf16x8*)&hb[p][c][(kt << 5) + (q << 3)];
          #pragma unroll
          for (int gi = 0; gi < 4; ++gi)
            #pragma unroll
            for (int ct = 0; ct < 2; ++ct)
              acc[gi][ct] = __builtin_amdgcn_mfma_f32_16x16x32_bf16(af, wf[gi][ct][kt], acc[gi][ct], 0, 0, 0);
        }
        #pragma unroll
        for (int ct = 0; ct < 2; ++ct){
          const int uc = u0 + (ct << 4);
          #pragma unroll
          for (int r = 0; r < 4; ++r){
            float si = sigm(acc[0][ct][r]);
            float sf = sigm(acc[1][ct][r]);
            float tg = tanh_(acc[2][ct][r]);
            float so = sigm(acc[3][ct][r]);
            float c2 = sf * c1[ct][r] + si * tg;
            float a1 = fmaxf(fmaf(dv[r], tdw[ct], tdbv[ct]), 0.f);
            float gam = __builtin_amdgcn_exp2f(-a1 * L2E);
            c1[ct][r] = c2;
            hb [p ^ 1][q4 + r][uc] = f2bf(so * tanh_(c2) * gam);
            cst[p ^ 1][q4 + r][uc] = c2;
          }
        }
      } else {
        // ---- per-chunk flush (wave 7, tt==1): x_c + loss for chunk cc-1.
        //      xh_hist row15 written by w4 at tt==0 (one barrier ago); sA[cb^1]
        //      still holds chunk cc-1. Stores/atomics drain under later compute.
        if (w == 7 && tt == 1 && cc > 0){
          const int obase = (cc - 1) << 4;
          const int pb = cb ^ 1;
          const int m = l >> 2, j = l & 3;
          f32x4 st, wse, sm;
          #pragma unroll
          for (int k = 0; k < 4; ++k){
            const int t2 = (j << 2) + k;
            float xy2 = sA[pb][2][t2][m];
            float mm2 = sA[pb][3][t2][m];
            float xh2 = xh_hist[t2][m];
            st[k]  = mm2 * xy2 + (1.f - mm2) * xh2;
            float d2 = xy2 - xh2;
            wse[k] = d2 * d2 * mm2;
            sm[k]  = mm2;
          }
          *((f32x4*)&out[1 + (bb + m) * 2048LL + obase + (j << 2)]) = st;
          #pragma unroll
          for (int mk = 4; mk <= 32; mk <<= 1){
            #pragma unroll
            for (int k = 0; k < 4; ++k){ wse[k] += __shfl_xor(wse[k], mk); sm[k] += __shfl_xor(sm[k], mk); }
          }
          if (l < 4){
            #pragma unroll
            for (int k = 0; k < 4; ++k){
              atomicAdd(&lossws[((obase + (j << 2) + k) << 1)    ], wse[k]);
              atomicAdd(&lossws[((obase + (j << 2) + k) << 1) + 1], sm[k]);
            }
          }
        }

        // ================= cell0(s-1) : same A-operand hb[p] ====================
        f32x4 xh = { hrb, hrb, hrb, hrb };
        #pragma unroll
        for (int w2 = 0; w2 < 4; ++w2)
          xh += *(const f32x4*)&xh_part[p][w2][q4];
        f32x4 xy = *(const f32x4*)&sA[ob][2][ott][q4];
        f32x4 mm = *(const f32x4*)&sA[ob][3][ott][q4];
        f32x4 xcv = mm * xy + (1.f - mm) * xh;
        if (w == 4 && c == 0 && s > 0) *((f32x4*)&xh_hist[ott][q4]) = xh;

        f32x4 acc[4][2];
        #pragma unroll
        for (int gi = 0; gi < 4; ++gi)
          #pragma unroll
          for (int ct = 0; ct < 2; ++ct)
            #pragma unroll
            for (int r = 0; r < 4; ++r)
              acc[gi][ct][r] = fmaf(xcv[r], wi[gi][ct][0], fmaf(mm[r], wi[gi][ct][1], bs[gi][ct]));
        #pragma unroll
        for (int kt = 0; kt < 4; ++kt){
          bf16x8 af = *(const bf16x8*)&hb[p][c][(kt << 5) + (q << 3)];
          #pragma unroll
          for (int gi = 0; gi < 4; ++gi)
            #pragma unroll
            for (int ct = 0; ct < 2; ++ct)
              acc[gi][ct] = __builtin_amdgcn_mfma_f32_16x16x32_bf16(af, wf[gi][ct][kt], acc[gi][ct], 0, 0, 0);
        }
        f32x4 pv = {0.f, 0.f, 0.f, 0.f};
        #pragma unroll
        for (int ct = 0; ct < 2; ++ct){
          const int uc = u0 + (ct << 4);
          #pragma unroll
          for (int r = 0; r < 4; ++r){
            float si = sigm(acc[0][ct][r]);
            float sf = sigm(acc[1][ct][r]);
            float tg = tanh_(acc[2][ct][r]);
            float so = sigm(acc[3][ct][r]);
            float c0n = sf * cst[p][q4 + r][uc] + si * tg;   // c-input = c1n(s-1)
            pv[r] += so * tanh_(c0n) * hrw[ct];
          }
        }
        #pragma unroll
        for (int mk = 1; mk < 16; mk <<= 1){
          #pragma unroll
          for (int r = 0; r < 4; ++r) pv[r] += __shfl_xor(pv[r], mk);
        }
        if (c == 0 && s > 0) *((f32x4*)&xh_part[p ^ 1][wv][q4]) = pv;
      }

      // ---- prefetch next chunk late (3-iteration live range)
      if (tt == 12 && cc + 1 < 128 && tid < 448){
        long long t0 = (long long)(cc + 1) * 16;
        nst = *(const f32x4*)(ldbase + (isM ? t0 : t0 * 3));
      }
      if (tt == 15 && cc + 1 < 128 && tid < 448) write_stage(cb ^ 1, nst);

      wg_barrier();   // the ONLY barrier per step (lgkm-only)
    }
  }

  // ---- epilogue: x_h(2047) from xh_part[0] (written at s=2047 -> parity 0),
  //      then flush the final chunk (sA buf 1, obase 2032).
  if (w == 4){
    f32x4 xh = { hrb, hrb, hrb, hrb };
    #pragma unroll
    for (int w2 = 0; w2 < 4; ++w2)
      xh += *(const f32x4*)&xh_part[0][w2][q4];
    if (c == 0) *((f32x4*)&xh_hist[15][q4]) = xh;
  }
  wg_barrier();
  if (w == 7){
    const int obase = 2032;
    const int m = l >> 2, j = l & 3;
    f32x4 st, wse, sm;
    #pragma unroll
    for (int k = 0; k < 4; ++k){
      const int t2 = (j << 2) + k;
      float xy2 = sA[1][2][t2][m];
      float mm2 = sA[1][3][t2][m];
      float xh2 = xh_hist[t2][m];
      st[k]  = mm2 * xy2 + (1.f - mm2) * xh2;
      float d2 = xy2 - xh2;
      wse[k] = d2 * d2 * mm2;
      sm[k]  = mm2;
    }
    *((f32x4*)&out[1 + (bb + m) * 2048LL + obase + (j << 2)]) = st;
    #pragma unroll
    for (int mk = 4; mk <= 32; mk <<= 1){
      #pragma unroll
      for (int k = 0; k < 4; ++k){ wse[k] += __shfl_xor(wse[k], mk); sm[k] += __shfl_xor(sm[k], mk); }
    }
    if (l < 4){
      #pragma unroll
      for (int k = 0; k < 4; ++k){
        atomicAdd(&lossws[((obase + (j << 2) + k) << 1)    ], wse[k]);
        atomicAdd(&lossws[((obase + (j << 2) + k) << 1) + 1], sm[k]);
      }
    }
  }
}

__global__ void loss_reduce(const float* __restrict__ lossws, float* __restrict__ out){
  __shared__ float red[1024];
  int t = threadIdx.x;
  float v = lossws[2 * t] / (lossws[2 * t + 1] + 1e-5f)
          + lossws[2 * (t + 1024)] / (lossws[2 * (t + 1024) + 1] + 1e-5f);
  red[t] = v;
  __syncthreads();
  for (int s = 512; s > 0; s >>= 1){
    if (t < s) red[t] += red[t + s];
    __syncthreads();
  }
  if (t == 0) out[0] = red[0];
}

__global__ void copy_outs(const float* __restrict__ values, const float* __restrict__ masks,
                          const float* __restrict__ evalm, float* __restrict__ out){
  const long long M = 8388608LL; // 4096*2048
  long long i = (long long)blockIdx.x * 256 + threadIdx.x;
  if (i < M){
    out[1 + M     + i] = evalm[i];
    out[1 + 2 * M + i] = values[3 * i + 2];
    out[1 + 3 * M + i] = masks[i];
  }
}

extern "C" void kernel_launch(void* const* d_in, const int* in_sizes, int n_in,
                              void* d_out, int out_size, void* d_ws, size_t ws_size,
                              hipStream_t stream){
  const float* values = (const float*)d_in[0];
  const float* masks  = (const float*)d_in[1];
  const float* deltas = (const float*)d_in[2];
  const float* evalm  = (const float*)d_in[3];
  const float* Wih0   = (const float*)d_in[4];
  const float* Whh0   = (const float*)d_in[5];
  const float* bih0   = (const float*)d_in[6];
  const float* bhh0   = (const float*)d_in[7];
  const float* Wih1   = (const float*)d_in[8];
  const float* Whh1   = (const float*)d_in[9];
  const float* bih1   = (const float*)d_in[10];
  const float* bhh1   = (const float*)d_in[11];
  const float* td_W   = (const float*)d_in[12];
  const float* td_b   = (const float*)d_in[13];
  const float* hr_W   = (const float*)d_in[14];
  const float* hr_b   = (const float*)d_in[15];
  float* out    = (float*)d_out;
  float* lossws = (float*)d_ws;

  hipMemsetAsync(lossws, 0, 2048 * 2 * sizeof(float), stream);
  hipLaunchKernelGGL(copy_outs, dim3(32768), dim3(256), 0, stream, values, masks, evalm, out);
  hipLaunchKernelGGL(rios_main, dim3(256), dim3(512), 0, stream,
                     values, masks, deltas, Wih0, Whh0, bih0, bhh0,
                     Wih1, Whh1, bih1, bhh1, td_W, td_b, hr_W, hr_b, out, lossws);
  hipLaunchKernelGGL(loss_reduce, dim3(1), dim3(1024), 0, stream, lossws, out);
}

// Round 6
// 8662.087 us; speedup vs baseline: 1.6254x; 1.6254x over previous
//
#include <hip/hip_runtime.h>

typedef __attribute__((ext_vector_type(8))) short bf16x8;
typedef __attribute__((ext_vector_type(4))) float f32x4;

#define L2E 1.4426950408889634f

__device__ __forceinline__ short f2bf(float x){
  unsigned u = __builtin_bit_cast(unsigned, x);
  u += 0x7fffu + ((u >> 16) & 1u);
  return (short)(u >> 16);
}
__device__ __forceinline__ float sigm(float x){
  float e = __builtin_amdgcn_exp2f(-x * L2E);
  return __builtin_amdgcn_rcpf(1.0f + e);
}
__device__ __forceinline__ float tanh_(float x){
  float e = __builtin_amdgcn_exp2f(x * (2.0f * L2E));
  return 1.0f - 2.0f * __builtin_amdgcn_rcpf(1.0f + e);
}

// LDS-only barrier: drain DS ops, raw s_barrier, NO vmcnt(0) drain -- global
// stores/atomics/prefetches stay in flight across steps.
__device__ __forceinline__ void wg_barrier(){
  asm volatile("s_waitcnt lgkmcnt(0)" ::: "memory");
  __builtin_amdgcn_s_barrier();
  asm volatile("" ::: "memory");
}

// r0's proven no-spill structure (two phases, two barriers per step, per-thread
// weights for BOTH cells: 128 AGPR wf + <=128 VGPR working set, FETCH ~= ideal),
// with the ONLY change being removal of per-step global memory ops:
//  - wave0 buffers x_c and loss partials in chunk-parity LDS (xc_hist / loss_s)
//  - wave7 flushes the previous chunk once per 16 steps (coalesced f32x4 stores
//    + 32 spread atomics, fire-and-forget under lgkm-only barriers)
// r3/r4/r5 lesson: every structure that exceeded the register budget spilled
// loop-invariants and paid multi-GB per-step HBM reloads on the serial chain.
// This delta strictly REDUCES per-step register pressure vs r0.
__global__ __launch_bounds__(512, 2)
void rios_main(const float* __restrict__ values, const float* __restrict__ masks,
               const float* __restrict__ deltas,
               const float* __restrict__ Wih0, const float* __restrict__ Whh0,
               const float* __restrict__ bih0, const float* __restrict__ bhh0,
               const float* __restrict__ Wih1, const float* __restrict__ Whh1,
               const float* __restrict__ bih1, const float* __restrict__ bhh1,
               const float* __restrict__ td_W, const float* __restrict__ td_b,
               const float* __restrict__ hr_W, const float* __restrict__ hr_b,
               float* __restrict__ out, float* __restrict__ lossws)
{
  __shared__ short hb[2][16][136];   // h A-operand ping-pong: [buf][batch m][unit k], +8 pad
  __shared__ float xh_part[8][16];   // per-wave partial of h0 . hr_W, per batch m
  __shared__ float sA[2][5][16][16]; // scalar chunks: [buf][v0,v1,v2,mask,delta2][tt][m]
  __shared__ float xc_hist[2][16][16]; // x_c by chunk parity: [buf][tt][m] (wave0 writes)
  __shared__ float loss_s[2][16][2];   // loss partials by chunk parity (wave0 writes)

  const int tid = threadIdx.x;
  const int w  = tid >> 6;
  const int l  = tid & 63;
  const int q  = l >> 4;
  const int c  = l & 15;
  const int q4 = q << 2;
  const int u  = (w << 4) + c;
  const long long bb = (long long)blockIdx.x * 16;

  // ---- persistent weight fragments (B-operand layout: col=lane&15, k=(lane>>4)*8+j)
  bf16x8 wf[2][4][4];   // [cell: 0=lstm1, 1=lstm0][gate][ktile]
  {
    const float* WhhA[2] = { Whh1, Whh0 };
    #pragma unroll
    for (int cell = 0; cell < 2; ++cell)
      #pragma unroll
      for (int gi = 0; gi < 4; ++gi)
        #pragma unroll
        for (int kt = 0; kt < 4; ++kt){
          const float* rp = WhhA[cell] + (((gi << 7) + u) << 7) + (kt << 5) + (q << 3);
          bf16x8 f;
          #pragma unroll
          for (int j = 0; j < 8; ++j) f[j] = f2bf(rp[j]);
          wf[cell][gi][kt] = f;
        }
  }
  float wi[2][4][2], bs[2][4];
  {
    const float* WihA[2] = { Wih1, Wih0 };
    const float* bihA[2] = { bih1, bih0 };
    const float* bhhA[2] = { bhh1, bhh0 };
    #pragma unroll
    for (int cell = 0; cell < 2; ++cell)
      #pragma unroll
      for (int gi = 0; gi < 4; ++gi){
        int rg = (gi << 7) + u;
        wi[cell][gi][0] = WihA[cell][rg * 2];
        wi[cell][gi][1] = WihA[cell][rg * 2 + 1];
        bs[cell][gi]    = bihA[cell][rg] + bhhA[cell][rg];
      }
  }
  const float tdw = td_W[u], tdbv = td_b[u], hrw = hr_W[u], hrb = hr_b[0];

  // ---- zero initial state in LDS
  {
    short* hz = &hb[0][0][0];
    for (int i = tid; i < 16 * 136; i += 512) hz[i] = 0;
    if (tid < 128) ((float*)xh_part)[tid] = 0.f;
  }

  // ---- chunk loader thread roles (16 steps of scalars per chunk)
  const int isV = (tid < 192);
  const int isD = (tid >= 192 && tid < 384);
  const int isM = (tid >= 384 && tid < 448);
  int lb = 0, lp = 0;
  if (isV){ lb = tid / 12;        lp = tid % 12; }
  else if (isD){ lb = (tid-192)/12; lp = (tid-192)%12; }
  else if (isM){ lb = (tid-384)/4;  lp = (tid-384)%4; }
  const float* ldbase = nullptr;
  if (isV)      ldbase = values + ((bb + lb) * 2048LL) * 3 + lp * 4;
  else if (isD) ldbase = deltas + ((bb + lb) * 2048LL) * 3 + lp * 4;
  else if (isM) ldbase = masks  +  (bb + lb) * 2048LL      + lp * 4;

  auto write_stage = [&](int buf, f32x4 r){
    if (isV){
      #pragma unroll
      for (int j = 0; j < 4; ++j){ int idx = lp * 4 + j; sA[buf][idx % 3][idx / 3][lb] = r[j]; }
    } else if (isD){
      #pragma unroll
      for (int j = 0; j < 4; ++j){ int idx = lp * 4 + j; if (idx % 3 == 2) sA[buf][4][idx / 3][lb] = r[j]; }
    } else if (isM){
      #pragma unroll
      for (int j = 0; j < 4; ++j){ sA[buf][3][lp * 4 + j][lb] = r[j]; }
    }
  };

  // prologue: chunk 0
  if (tid < 448){
    f32x4 st = *(const f32x4*)(ldbase);
    write_stage(0, st);
  }
  __syncthreads();

  f32x4 c1 = {0.f, 0.f, 0.f, 0.f};

  for (int cc = 0; cc < 128; ++cc){
    const int cb = cc & 1;
    f32x4 nst;
    if (cc + 1 < 128 && tid < 448){
      long long t0 = (long long)(cc + 1) * 16;
      nst = *(const f32x4*)(ldbase + (isM ? t0 : t0 * 3));
    }
    #pragma unroll 2
    for (int tt = 0; tt < 16; ++tt){
      const int p = tt & 1;

      // ---- per-chunk flush (wave7, tt==0): previous chunk's x_c + loss partials,
      //      from the OTHER parity buffers. Fire-and-forget (no vmcnt at barriers).
      if (w == 7 && tt == 0 && cc > 0){
        const int obase = (cc - 1) << 4;
        const int pb = cb ^ 1;
        const int m = l >> 2, j = l & 3;
        f32x4 st;
        #pragma unroll
        for (int k = 0; k < 4; ++k) st[k] = xc_hist[pb][(j << 2) + k][m];
        *((f32x4*)&out[1 + (bb + m) * 2048LL + obase + (j << 2)]) = st;
        if (l < 32) atomicAdd(&lossws[(obase << 1) + l], ((const float*)&loss_s[pb][0][0])[l]);
      }

      // ================= phase A : cell1 (+ wave0: x_h / x_c / loss) ===========
      f32x4 v0v = *(const f32x4*)&sA[cb][0][tt][q4];
      f32x4 v1v = *(const f32x4*)&sA[cb][1][tt][q4];
      f32x4 dv  = *(const f32x4*)&sA[cb][4][tt][q4];
      f32x4 acc[4];
      #pragma unroll
      for (int gi = 0; gi < 4; ++gi){
        #pragma unroll
        for (int r = 0; r < 4; ++r)
          acc[gi][r] = fmaf(v0v[r], wi[0][gi][0], fmaf(v1v[r], wi[0][gi][1], bs[0][gi]));
      }
      #pragma unroll
      for (int kt = 0; kt < 4; ++kt){
        bf16x8 af = *(const bf16x8*)&hb[p][c][(kt << 5) + (q << 3)];
        #pragma unroll
        for (int gi = 0; gi < 4; ++gi)
          acc[gi] = __builtin_amdgcn_mfma_f32_16x16x32_bf16(af, wf[0][gi][kt], acc[gi], 0, 0, 0);
      }

      if (w == 0){
        f32x4 xh = { hrb, hrb, hrb, hrb };
        #pragma unroll
        for (int w2 = 0; w2 < 8; ++w2)
          xh += *(const f32x4*)&xh_part[w2][q4];
        f32x4 xy = *(const f32x4*)&sA[cb][2][tt][q4];
        f32x4 mm = *(const f32x4*)&sA[cb][3][tt][q4];
        f32x4 xc = mm * xy + (1.f - mm) * xh;
        f32x4 df = xy - xh;
        f32x4 wv = df * df * mm;
        if (c == 0) *((f32x4*)&xc_hist[cb][tt][q4]) = xc;
        float swse = wv[0] + wv[1] + wv[2] + wv[3];
        float smm  = mm[0] + mm[1] + mm[2] + mm[3];
        swse += __shfl_xor(swse, 16); swse += __shfl_xor(swse, 32);
        smm  += __shfl_xor(smm, 16);  smm  += __shfl_xor(smm, 32);
        if (l == 0){ loss_s[cb][tt][0] = swse; loss_s[cb][tt][1] = smm; }
      }

      #pragma unroll
      for (int r = 0; r < 4; ++r){
        float si = sigm(acc[0][r]);
        float sf = sigm(acc[1][r]);
        float tg = tanh_(acc[2][r]);
        float so = sigm(acc[3][r]);
        float c2 = sf * c1[r] + si * tg;
        float a1 = fmaxf(fmaf(dv[r], tdw, tdbv), 0.f);
        float gam = __builtin_amdgcn_exp2f(-a1 * L2E);
        float h1n = so * tanh_(c2) * gam;
        c1[r] = c2;
        hb[p ^ 1][q4 + r][u] = f2bf(h1n);
      }
      wg_barrier();   // barrier 1: h1n + xc_hist/loss_s published

      // ================= phase B : cell0 =======================================
      f32x4 xcv = *(const f32x4*)&xc_hist[cb][tt][q4];
      f32x4 mmv = *(const f32x4*)&sA[cb][3][tt][q4];
      #pragma unroll
      for (int gi = 0; gi < 4; ++gi){
        #pragma unroll
        for (int r = 0; r < 4; ++r)
          acc[gi][r] = fmaf(xcv[r], wi[1][gi][0], fmaf(mmv[r], wi[1][gi][1], bs[1][gi]));
      }
      #pragma unroll
      for (int kt = 0; kt < 4; ++kt){
        bf16x8 af = *(const bf16x8*)&hb[p ^ 1][c][(kt << 5) + (q << 3)];
        #pragma unroll
        for (int gi = 0; gi < 4; ++gi)
          acc[gi] = __builtin_amdgcn_mfma_f32_16x16x32_bf16(af, wf[1][gi][kt], acc[gi], 0, 0, 0);
      }
      f32x4 pv;
      #pragma unroll
      for (int r = 0; r < 4; ++r){
        float si = sigm(acc[0][r]);
        float sf = sigm(acc[1][r]);
        float tg = tanh_(acc[2][r]);
        float so = sigm(acc[3][r]);
        float c0n = sf * c1[r] + si * tg;   // c input = c1n (updated), not overwritten
        float h0n = so * tanh_(c0n);
        pv[r] = h0n * hrw;
      }
      #pragma unroll
      for (int mk = 1; mk < 16; mk <<= 1){
        #pragma unroll
        for (int r = 0; r < 4; ++r) pv[r] += __shfl_xor(pv[r], mk);
      }
      if (c == 0) *((f32x4*)&xh_part[w][q4]) = pv;
      wg_barrier();   // barrier 2: xh_part published for next step
    }
    if (cc + 1 < 128 && tid < 448) write_stage(cb ^ 1, nst);
    wg_barrier();     // publish next scalar chunk
  }

  // ---- epilogue: flush the final chunk (cc=127 -> parity buffers [1])
  if (w == 7){
    const int obase = 2032;
    const int m = l >> 2, j = l & 3;
    f32x4 st;
    #pragma unroll
    for (int k = 0; k < 4; ++k) st[k] = xc_hist[1][(j << 2) + k][m];
    *((f32x4*)&out[1 + (bb + m) * 2048LL + obase + (j << 2)]) = st;
    if (l < 32) atomicAdd(&lossws[(obase << 1) + l], ((const float*)&loss_s[1][0][0])[l]);
  }
}

__global__ void loss_reduce(const float* __restrict__ lossws, float* __restrict__ out){
  __shared__ float red[1024];
  int t = threadIdx.x;
  float v = lossws[2 * t] / (lossws[2 * t + 1] + 1e-5f)
          + lossws[2 * (t + 1024)] / (lossws[2 * (t + 1024) + 1] + 1e-5f);
  red[t] = v;
  __syncthreads();
  for (int s = 512; s > 0; s >>= 1){
    if (t < s) red[t] += red[t + s];
    __syncthreads();
  }
  if (t == 0) out[0] = red[0];
}

__global__ void copy_outs(const float* __restrict__ values, const float* __restrict__ masks,
                          const float* __restrict__ evalm, float* __restrict__ out){
  const long long M = 8388608LL; // 4096*2048
  long long i = (long long)blockIdx.x * 256 + threadIdx.x;
  if (i < M){
    out[1 + M     + i] = evalm[i];
    out[1 + 2 * M + i] = values[3 * i + 2];
    out[1 + 3 * M + i] = masks[i];
  }
}

extern "C" void kernel_launch(void* const* d_in, const int* in_sizes, int n_in,
                              void* d_out, int out_size, void* d_ws, size_t ws_size,
                              hipStream_t stream){
  const float* values = (const float*)d_in[0];
  const float* masks  = (const float*)d_in[1];
  const float* deltas = (const float*)d_in[2];
  const float* evalm  = (const float*)d_in[3];
  const float* Wih0   = (const float*)d_in[4];
  const float* Whh0   = (const float*)d_in[5];
  const float* bih0   = (const float*)d_in[6];
  const float* bhh0   = (const float*)d_in[7];
  const float* Wih1   = (const float*)d_in[8];
  const float* Whh1   = (const float*)d_in[9];
  const float* bih1   = (const float*)d_in[10];
  const float* bhh1   = (const float*)d_in[11];
  const float* td_W   = (const float*)d_in[12];
  const float* td_b   = (const float*)d_in[13];
  const float* hr_W   = (const float*)d_in[14];
  const float* hr_b   = (const float*)d_in[15];
  float* out    = (float*)d_out;
  float* lossws = (float*)d_ws;

  hipMemsetAsync(lossws, 0, 2048 * 2 * sizeof(float), stream);
  hipLaunchKernelGGL(copy_outs, dim3(32768), dim3(256), 0, stream, values, masks, evalm, out);
  hipLaunchKernelGGL(rios_main, dim3(256), dim3(512), 0, stream,
                     values, masks, deltas, Wih0, Whh0, bih0, bhh0,
                     Wih1, Whh1, bih1, bhh1, td_W, td_b, hr_W, hr_b, out, lossws);
  hipLaunchKernelGGL(loss_reduce, dim3(1), dim3(1024), 0, stream, lossws, out);
}